// Round 2
// baseline (411.239 us; speedup 1.0000x reference)
//
#include <hip/hip_runtime.h>

using short8 = __attribute__((ext_vector_type(8))) short;
using f32x4  = __attribute__((ext_vector_type(4))) float;

__device__ __forceinline__ float bf2f(unsigned short u) {
  union { unsigned int i; float f; } c; c.i = ((unsigned int)u) << 16; return c.f;
}
__device__ __forceinline__ unsigned short f2bf(float x) {
  union { float f; unsigned int i; } c; c.f = x;
  unsigned int r = c.i + 0x7fffu + ((c.i >> 16) & 1u);
  return (unsigned short)(r >> 16);
}

// ---------------- cast kernels ----------------
__global__ void cast2_kernel(const float* __restrict__ a, const float* __restrict__ b,
                             unsigned short* __restrict__ oa, unsigned short* __restrict__ ob,
                             int n4) {
  int stride = gridDim.x * blockDim.x;
  for (int i = blockIdx.x * blockDim.x + threadIdx.x; i < 2 * n4; i += stride) {
    const float4* s; ushort4* d; int j;
    if (i < n4) { s = (const float4*)a; d = (ushort4*)oa; j = i; }
    else        { s = (const float4*)b; d = (ushort4*)ob; j = i - n4; }
    float4 v = s[j];
    ushort4 o; o.x = f2bf(v.x); o.y = f2bf(v.y); o.z = f2bf(v.z); o.w = f2bf(v.w);
    d[j] = o;
  }
}

__global__ void castw_kernel(const float* __restrict__ wq, const float* __restrict__ wk,
                             const float* __restrict__ wv, const float* __restrict__ wm,
                             const float* __restrict__ w1, const float* __restrict__ w2,
                             unsigned short* __restrict__ dst) {
  int i = blockIdx.x * blockDim.x + threadIdx.x;  // total 655360
  if (i >= 655360) return;
  const float* s; int off;
  if      (i < 65536)  { s = wq; off = i; }
  else if (i < 131072) { s = wk; off = i - 65536; }
  else if (i < 196608) { s = wv; off = i - 131072; }
  else if (i < 262144) { s = wm; off = i - 196608; }
  else if (i < 524288) { s = w1; off = i - 262144; }
  else                 { s = w2; off = i - 524288; }
  dst[i] = f2bf(s[off]);
}

// ---------------- GEMM: C[M,O] = A[M,K] @ B[O,K]^T, bf16 in, f32 accum ----------------
enum { EPI_F32 = 0, EPI_ELU1_MASK = 1, EPI_KV = 2, EPI_RELU_BF16 = 3 };

template<int EPI, bool SPLITA>
__global__ __launch_bounds__(256)
void gemm_nt(const unsigned short* __restrict__ A, const unsigned short* __restrict__ A2,
             const unsigned short* __restrict__ B,
             void* __restrict__ C0, void* __restrict__ C1, const float* __restrict__ aux,
             int M, int O, int K, float scale) {
  __shared__ unsigned short As[128 * 64];
  __shared__ unsigned short Bs[128 * 64];
  const int t  = threadIdx.x;
  const int w  = t >> 6, l = t & 63;
  const int wr = w >> 1, wc = w & 1;
  const int lr = l & 15, kg = l >> 4;
  const int brow = blockIdx.x * 128, bcol = blockIdx.y * 128;
  const int rsub = l >> 3;                       // 0..7 (row within 8-row chunk)
  const int swz  = 8 * ((l & 7) ^ rsub);         // pre-swizzled source col (elems)

  f32x4 acc[4][4];
  f32x4 zero = {0.f, 0.f, 0.f, 0.f};
  #pragma unroll
  for (int m = 0; m < 4; m++)
    #pragma unroll
    for (int n = 0; n < 4; n++) acc[m][n] = zero;

  for (int k0 = 0; k0 < K; k0 += 64) {
    #pragma unroll
    for (int i = 0; i < 4; i++) {
      int c = w * 4 + i;                         // chunk 0..15, 1KB each
      int row = c * 8 + rsub;
      const unsigned short* ga;
      if (SPLITA) {
        const unsigned short* base = (k0 < 256) ? A : A2;
        ga = base + (size_t)(brow + row) * 256 + (k0 & 255) + swz;
      } else {
        ga = A + (size_t)(brow + row) * K + k0 + swz;
      }
      const unsigned short* gb = B + (size_t)(bcol + row) * K + k0 + swz;
      __builtin_amdgcn_global_load_lds((__attribute__((address_space(1))) unsigned int*)ga,
          (__attribute__((address_space(3))) unsigned int*)(As + c * 512), 16, 0, 0);
      __builtin_amdgcn_global_load_lds((__attribute__((address_space(1))) unsigned int*)gb,
          (__attribute__((address_space(3))) unsigned int*)(Bs + c * 512), 16, 0, 0);
    }
    __syncthreads();
    #pragma unroll
    for (int kk = 0; kk < 2; kk++) {
      short8 af[4], bfr[4];
      #pragma unroll
      for (int m = 0; m < 4; m++) {
        int r = wr * 64 + m * 16 + lr;
        int cb = kk * 64 + kg * 16;
        af[m] = *(const short8*)((const char*)As + r * 128 + (cb ^ ((r & 7) << 4)));
      }
      #pragma unroll
      for (int n = 0; n < 4; n++) {
        int r = wc * 64 + n * 16 + lr;
        int cb = kk * 64 + kg * 16;
        bfr[n] = *(const short8*)((const char*)Bs + r * 128 + (cb ^ ((r & 7) << 4)));
      }
      #pragma unroll
      for (int m = 0; m < 4; m++)
        #pragma unroll
        for (int n = 0; n < 4; n++)
          acc[m][n] = __builtin_amdgcn_mfma_f32_16x16x32_bf16(af[m], bfr[n], acc[m][n], 0, 0, 0);
    }
    __syncthreads();
  }

  #pragma unroll
  for (int m = 0; m < 4; m++) {
    #pragma unroll
    for (int n = 0; n < 4; n++) {
      int col = bcol + wc * 64 + n * 16 + lr;
      #pragma unroll
      for (int j = 0; j < 4; j++) {
        int row = brow + wr * 64 + m * 16 + kg * 4 + j;
        float v = acc[m][n][j];
        if (EPI == EPI_F32) {
          ((float*)C0)[(size_t)row * O + col] = v;
        } else if (EPI == EPI_ELU1_MASK) {
          float e = v > 0.f ? v + 1.f : __expf(v);   // elu(v)+1
          ((unsigned short*)C0)[(size_t)row * O + col] = f2bf(e * aux[row]);
        } else if (EPI == EPI_KV) {
          int colm = col & 255;
          if (col < 256) {                           // K path: elu+1, mask
            float e = v > 0.f ? v + 1.f : __expf(v);
            ((unsigned short*)C0)[(size_t)row * 256 + colm] = f2bf(e * aux[row]);
          } else {                                   // V path: mask * 1/S
            ((unsigned short*)C1)[(size_t)row * 256 + colm] = f2bf(v * aux[row] * scale);
          }
        } else {  // EPI_RELU_BF16
          ((unsigned short*)C0)[(size_t)row * O + col] = f2bf(v > 0.f ? v : 0.f);
        }
      }
    }
  }
}

// ---------------- KVt[nh][dv][d] = sum_s V[s][dv] K[s][d];  Ksum[n][c] = sum_s K[s][c] ----------------
__global__ __launch_bounds__(1024)
void kv_reduce(const unsigned short* __restrict__ Kb, const unsigned short* __restrict__ Vb,
               float* __restrict__ KVt, float* __restrict__ Ksum) {
  __shared__ float Ks[16][256];
  __shared__ float Vs[16][256];
  const int t  = threadIdx.x;
  const int n  = blockIdx.x >> 6;
  const int s0 = (blockIdx.x & 63) * 128;
  const int h  = t >> 7, g = (t >> 5) & 3, dv = t & 31;
  const int r16 = t >> 6, c4 = (t & 63) * 4;
  const int cbase = h * 32;
  f32x4 acc0 = {0.f, 0.f, 0.f, 0.f}, acc1 = {0.f, 0.f, 0.f, 0.f};
  float ks = 0.f;

  for (int tile = 0; tile < 8; ++tile) {
    int s = s0 + tile * 16;
    size_t gbase = ((size_t)(n * 8192 + s + r16)) * 256 + c4;
    ushort4 kk = *(const ushort4*)&Kb[gbase];
    ushort4 vv = *(const ushort4*)&Vb[gbase];
    __syncthreads();   // previous tile's compute done
    float4 kf; kf.x = bf2f(kk.x); kf.y = bf2f(kk.y); kf.z = bf2f(kk.z); kf.w = bf2f(kk.w);
    float4 vf; vf.x = bf2f(vv.x); vf.y = bf2f(vv.y); vf.z = bf2f(vv.z); vf.w = bf2f(vv.w);
    *(float4*)&Ks[r16][c4] = kf;
    *(float4*)&Vs[r16][c4] = vf;
    __syncthreads();   // tile visible
    if (t < 256) {
      #pragma unroll
      for (int r = 0; r < 16; ++r) ks += Ks[r][t];
    }
    #pragma unroll
    for (int si = 0; si < 16; ++si) {
      f32x4 k0 = *(const f32x4*)&Ks[si][cbase + g * 8];
      f32x4 k1 = *(const f32x4*)&Ks[si][cbase + g * 8 + 4];
      float vx = Vs[si][cbase + dv];
      acc0 += k0 * vx;
      acc1 += k1 * vx;
    }
  }
  float* dst = &KVt[(((size_t)(n * 8 + h) * 32 + dv) * 32) + g * 8];
  atomicAdd(dst + 0, acc0[0]); atomicAdd(dst + 1, acc0[1]);
  atomicAdd(dst + 2, acc0[2]); atomicAdd(dst + 3, acc0[3]);
  atomicAdd(dst + 4, acc1[0]); atomicAdd(dst + 5, acc1[1]);
  atomicAdd(dst + 6, acc1[2]); atomicAdd(dst + 7, acc1[3]);
  if (t < 256) atomicAdd(&Ksum[n * 256 + t], ks);
}

// ---------------- Mb[l, h*32+dv] = (q . KVt[h][dv][:]) * S / (q . Ksum[h] + eps) ----------------
__global__ __launch_bounds__(256)
void msg_apply(const unsigned short* __restrict__ Qb, const float* __restrict__ KVt,
               const float* __restrict__ Ksum, unsigned short* __restrict__ Mb) {
  __shared__ float KVs[8192];
  __shared__ float Kss[256];
  const int t = threadIdx.x;
  const int row0 = blockIdx.x * 32;
  const int n = blockIdx.x >> 8;
  const int r = t >> 3, h = t & 7;
  for (int i = t; i < 8192; i += 256) {
    int j = i ^ (((i >> 10) & 7) << 2);          // XOR d-slot with h: bank-spread
    KVs[j] = KVt[(size_t)n * 8192 + i];
  }
  Kss[t] = Ksum[n * 256 + t];
  __syncthreads();

  const unsigned short* qp = &Qb[(size_t)(row0 + r) * 256 + h * 32];
  float q[32];
  #pragma unroll
  for (int i = 0; i < 4; ++i) {
    short8 v = *(const short8*)(qp + i * 8);
    #pragma unroll
    for (int j = 0; j < 8; ++j) q[i * 8 + j] = bf2f((unsigned short)v[j]);
  }
  float zden = 0.f;
  #pragma unroll
  for (int sl = 0; sl < 8; ++sl) {
    f32x4 kv = *(const f32x4*)&Kss[h * 32 + sl * 4];
    zden += q[sl*4+0]*kv[0] + q[sl*4+1]*kv[1] + q[sl*4+2]*kv[2] + q[sl*4+3]*kv[3];
  }
  float z = 8192.f / (zden + 1e-6f);
  const int kvbase = h * 1024;
  short8 ov[4];
  #pragma unroll
  for (int dv = 0; dv < 32; ++dv) {
    float o = 0.f;
    #pragma unroll
    for (int sl = 0; sl < 8; ++sl) {
      f32x4 kv = *(const f32x4*)&KVs[kvbase + dv * 32 + ((sl ^ h) << 2)];
      o += q[sl*4+0]*kv[0] + q[sl*4+1]*kv[1] + q[sl*4+2]*kv[2] + q[sl*4+3]*kv[3];
    }
    ov[dv >> 3][dv & 7] = (short)f2bf(o * z);
  }
  unsigned short* op = (unsigned short*)&Mb[(size_t)(row0 + r) * 256 + h * 32];
  #pragma unroll
  for (int i = 0; i < 4; ++i) *(short8*)(op + i * 8) = ov[i];
}

// ---------------- LayerNorm kernels ----------------
__device__ __forceinline__ float block_sum(float v, float* red) {
  #pragma unroll
  for (int o = 32; o; o >>= 1) v += __shfl_down(v, o, 64);
  __syncthreads();
  if ((threadIdx.x & 63) == 0) red[threadIdx.x >> 6] = v;
  __syncthreads();
  return red[0] + red[1] + red[2] + red[3];
}

__global__ __launch_bounds__(256)
void ln1_msg(const float* __restrict__ msgf, const float* __restrict__ g,
             const float* __restrict__ b, unsigned short* __restrict__ msgb) {
  __shared__ float red[4];
  int row = blockIdx.x, t = threadIdx.x;
  float v = msgf[(size_t)row * 256 + t];
  float mu  = block_sum(v, red) * (1.f / 256.f);
  float dvv = v - mu;
  float var = block_sum(dvv * dvv, red) * (1.f / 256.f);
  float y = dvv * rsqrtf(var + 1e-5f) * g[t] + b[t];
  msgb[(size_t)row * 256 + t] = f2bf(y);
}

__global__ __launch_bounds__(256)
void ln2_res(const float* __restrict__ hbuf, const float* __restrict__ x,
             const float* __restrict__ g, const float* __restrict__ b,
             float* __restrict__ out) {
  __shared__ float red[4];
  int row = blockIdx.x, t = threadIdx.x;
  float v = hbuf[(size_t)row * 256 + t];
  float mu  = block_sum(v, red) * (1.f / 256.f);
  float dvv = v - mu;
  float var = block_sum(dvv * dvv, red) * (1.f / 256.f);
  float y = dvv * rsqrtf(var + 1e-5f) * g[t] + b[t];
  out[(size_t)row * 256 + t] = x[(size_t)row * 256 + t] + y;
}

// ---------------- launch ----------------
extern "C" void kernel_launch(void* const* d_in, const int* in_sizes, int n_in,
                              void* d_out, int out_size, void* d_ws, size_t ws_size,
                              hipStream_t stream) {
  const float* x   = (const float*)d_in[0];
  const float* src = (const float*)d_in[1];
  const float* xm  = (const float*)d_in[2];
  const float* sm  = (const float*)d_in[3];
  const float* Wq  = (const float*)d_in[4];
  const float* Wk  = (const float*)d_in[5];
  const float* Wv  = (const float*)d_in[6];
  const float* Wm  = (const float*)d_in[7];
  const float* W1  = (const float*)d_in[8];
  const float* W2  = (const float*)d_in[9];
  const float* g1  = (const float*)d_in[10];
  const float* b1  = (const float*)d_in[11];
  const float* g2  = (const float*)d_in[12];
  const float* b2  = (const float*)d_in[13];
  float* out = (float*)d_out;
  char*  ws  = (char*)d_ws;

  // workspace layout (bytes), regions reused over time:
  unsigned short* xb   = (unsigned short*)(ws);                    // 0..16M   bf16(x)
  unsigned short* sb   = (unsigned short*)(ws + 16777216);         // 16..32M  bf16(src)
  unsigned short* Qb   = (unsigned short*)(ws + 33554432);         // 32..48M
  unsigned short* Mb   = (unsigned short*)(ws + 50331648);         // 48..64M
  unsigned short* Kb   = (unsigned short*)(ws + 67108864);         // 64..80M
  unsigned short* Vb   = (unsigned short*)(ws + 83886080);         // 80..96M
  float*          msgf = (float*)(ws + 67108864);                  // 64..96M (after kv_reduce)
  unsigned short* msgb = (unsigned short*)(ws + 50331648);         // 48..64M (after merge gemm)
  unsigned short* h1b  = (unsigned short*)(ws + 67108864);         // 64..96M (after ln1)
  float*          h2f  = (float*)(ws);                             // 0..32M  (after mlp1)
  float*          KV   = (float*)(ws + 100663296);                 // 131072 B  (KVt[nh][dv][d])
  float*          Ksm  = (float*)(ws + 100663296 + 131072);        // 4096 B
  unsigned short* Wb   = (unsigned short*)(ws + 100663296 + 135168);
  unsigned short* Wqb = Wb;
  unsigned short* Wkb = Wb + 65536;    // Wk rows 0..255, Wv rows 256..511 (contiguous)
  unsigned short* Wmb = Wb + 196608;
  unsigned short* W1b = Wb + 262144;
  unsigned short* W2b = Wb + 524288;

  hipMemsetAsync(ws + 100663296, 0, 135168, stream);  // zero KVt + Ksum

  cast2_kernel<<<2048, 256, 0, stream>>>(x, src, xb, sb, 2097152);
  castw_kernel<<<2560, 256, 0, stream>>>(Wq, Wk, Wv, Wm, W1, W2, Wb);

  // projections: Q alone; K+V fused (O=512, B = [Wk;Wv])
  gemm_nt<EPI_ELU1_MASK, false><<<dim3(256, 2), 256, 0, stream>>>(
      xb, nullptr, Wqb, (void*)Qb, nullptr, xm, 32768, 256, 256, 0.f);
  gemm_nt<EPI_KV, false><<<dim3(256, 4), 256, 0, stream>>>(
      sb, nullptr, Wkb, (void*)Kb, (void*)Vb, sm, 32768, 512, 256, 1.f / 8192.f);

  // linear attention core
  kv_reduce<<<256, 1024, 0, stream>>>(Kb, Vb, KV, Ksm);
  msg_apply<<<1024, 256, 0, stream>>>(Qb, KV, Ksm, Mb);

  // merge heads + LN1
  gemm_nt<EPI_F32, false><<<dim3(256, 2), 256, 0, stream>>>(
      Mb, nullptr, Wmb, (void*)msgf, nullptr, nullptr, 32768, 256, 256, 0.f);
  ln1_msg<<<32768, 256, 0, stream>>>(msgf, g1, b1, msgb);

  // MLP: A split = [xb | msgb]
  gemm_nt<EPI_RELU_BF16, true><<<dim3(256, 4), 256, 0, stream>>>(
      xb, msgb, W1b, (void*)h1b, nullptr, nullptr, 32768, 512, 512, 0.f);
  gemm_nt<EPI_F32, false><<<dim3(256, 2), 256, 0, stream>>>(
      h1b, nullptr, W2b, (void*)h2f, nullptr, nullptr, 32768, 256, 512, 0.f);
  ln2_res<<<32768, 256, 0, stream>>>(h2f, x, g2, b2, out);
}

// Round 3
// 321.926 us; speedup vs baseline: 1.2774x; 1.2774x over previous
//
#include <hip/hip_runtime.h>

using short8 = __attribute__((ext_vector_type(8))) short;
using f32x4  = __attribute__((ext_vector_type(4))) float;

__device__ __forceinline__ float bf2f(unsigned short u) {
  union { unsigned int i; float f; } c; c.i = ((unsigned int)u) << 16; return c.f;
}
__device__ __forceinline__ unsigned short f2bf(float x) {
  union { float f; unsigned int i; } c; c.f = x;
  unsigned int r = c.i + 0x7fffu + ((c.i >> 16) & 1u);
  return (unsigned short)(r >> 16);
}

// ---------------- cast kernels ----------------
__global__ void cast2_kernel(const float* __restrict__ a, const float* __restrict__ b,
                             unsigned short* __restrict__ oa, unsigned short* __restrict__ ob,
                             int n4) {
  int stride = gridDim.x * blockDim.x;
  for (int i = blockIdx.x * blockDim.x + threadIdx.x; i < 2 * n4; i += stride) {
    const float4* s; ushort4* d; int j;
    if (i < n4) { s = (const float4*)a; d = (ushort4*)oa; j = i; }
    else        { s = (const float4*)b; d = (ushort4*)ob; j = i - n4; }
    float4 v = s[j];
    ushort4 o; o.x = f2bf(v.x); o.y = f2bf(v.y); o.z = f2bf(v.z); o.w = f2bf(v.w);
    d[j] = o;
  }
}

__global__ void castw_kernel(const float* __restrict__ wq, const float* __restrict__ wk,
                             const float* __restrict__ wv, const float* __restrict__ wm,
                             const float* __restrict__ w1, const float* __restrict__ w2,
                             unsigned short* __restrict__ dst) {
  int i = blockIdx.x * blockDim.x + threadIdx.x;  // total 655360
  if (i >= 655360) return;
  const float* s; int off;
  if      (i < 65536)  { s = wq; off = i; }
  else if (i < 131072) { s = wk; off = i - 65536; }
  else if (i < 196608) { s = wv; off = i - 131072; }
  else if (i < 262144) { s = wm; off = i - 196608; }
  else if (i < 524288) { s = w1; off = i - 262144; }
  else                 { s = w2; off = i - 524288; }
  dst[i] = f2bf(s[off]);
}

// ---------------- GEMM: C[M,O] = A[M,K] @ B[O,K]^T, bf16 in, f32 accum ----------------
enum { EPI_F32 = 0, EPI_ELU1_MASK = 1, EPI_KV = 2, EPI_RELU_BF16 = 3 };

template<int EPI, bool SPLITA>
__global__ __launch_bounds__(256)
void gemm_nt(const unsigned short* __restrict__ A, const unsigned short* __restrict__ A2,
             const unsigned short* __restrict__ B,
             void* __restrict__ C0, void* __restrict__ C1, const float* __restrict__ aux,
             int M, int O, int K, float scale) {
  __shared__ unsigned short As[128 * 64];
  __shared__ unsigned short Bs[128 * 64];
  const int t  = threadIdx.x;
  const int w  = t >> 6, l = t & 63;
  const int wr = w >> 1, wc = w & 1;
  const int lr = l & 15, kg = l >> 4;
  const int brow = blockIdx.x * 128, bcol = blockIdx.y * 128;
  const int rsub = l >> 3;                       // 0..7 (row within 8-row chunk)
  const int swz  = 8 * ((l & 7) ^ rsub);         // pre-swizzled source col (elems)

  f32x4 acc[4][4];
  f32x4 zero = {0.f, 0.f, 0.f, 0.f};
  #pragma unroll
  for (int m = 0; m < 4; m++)
    #pragma unroll
    for (int n = 0; n < 4; n++) acc[m][n] = zero;

  for (int k0 = 0; k0 < K; k0 += 64) {
    #pragma unroll
    for (int i = 0; i < 4; i++) {
      int c = w * 4 + i;                         // chunk 0..15, 1KB each
      int row = c * 8 + rsub;
      const unsigned short* ga;
      if (SPLITA) {
        const unsigned short* base = (k0 < 256) ? A : A2;
        ga = base + (size_t)(brow + row) * 256 + (k0 & 255) + swz;
      } else {
        ga = A + (size_t)(brow + row) * K + k0 + swz;
      }
      const unsigned short* gb = B + (size_t)(bcol + row) * K + k0 + swz;
      __builtin_amdgcn_global_load_lds((__attribute__((address_space(1))) unsigned int*)ga,
          (__attribute__((address_space(3))) unsigned int*)(As + c * 512), 16, 0, 0);
      __builtin_amdgcn_global_load_lds((__attribute__((address_space(1))) unsigned int*)gb,
          (__attribute__((address_space(3))) unsigned int*)(Bs + c * 512), 16, 0, 0);
    }
    __syncthreads();
    #pragma unroll
    for (int kk = 0; kk < 2; kk++) {
      short8 af[4], bfr[4];
      #pragma unroll
      for (int m = 0; m < 4; m++) {
        int r = wr * 64 + m * 16 + lr;
        int cb = kk * 64 + kg * 16;
        af[m] = *(const short8*)((const char*)As + r * 128 + (cb ^ ((r & 7) << 4)));
      }
      #pragma unroll
      for (int n = 0; n < 4; n++) {
        int r = wc * 64 + n * 16 + lr;
        int cb = kk * 64 + kg * 16;
        bfr[n] = *(const short8*)((const char*)Bs + r * 128 + (cb ^ ((r & 7) << 4)));
      }
      #pragma unroll
      for (int m = 0; m < 4; m++)
        #pragma unroll
        for (int n = 0; n < 4; n++)
          acc[m][n] = __builtin_amdgcn_mfma_f32_16x16x32_bf16(af[m], bfr[n], acc[m][n], 0, 0, 0);
    }
    __syncthreads();
  }

  #pragma unroll
  for (int m = 0; m < 4; m++) {
    #pragma unroll
    for (int n = 0; n < 4; n++) {
      int col = bcol + wc * 64 + n * 16 + lr;
      #pragma unroll
      for (int j = 0; j < 4; j++) {
        int row = brow + wr * 64 + m * 16 + kg * 4 + j;
        float v = acc[m][n][j];
        if (EPI == EPI_F32) {
          ((float*)C0)[(size_t)row * O + col] = v;
        } else if (EPI == EPI_ELU1_MASK) {
          float e = v > 0.f ? v + 1.f : __expf(v);   // elu(v)+1
          ((unsigned short*)C0)[(size_t)row * O + col] = f2bf(e * aux[row]);
        } else if (EPI == EPI_KV) {
          int colm = col & 255;
          if (col < 256) {                           // K path: elu+1, mask
            float e = v > 0.f ? v + 1.f : __expf(v);
            ((unsigned short*)C0)[(size_t)row * 256 + colm] = f2bf(e * aux[row]);
          } else {                                   // V path: mask * 1/S
            ((unsigned short*)C1)[(size_t)row * 256 + colm] = f2bf(v * aux[row] * scale);
          }
        } else {  // EPI_RELU_BF16
          ((unsigned short*)C0)[(size_t)row * O + col] = f2bf(v > 0.f ? v : 0.f);
        }
      }
    }
  }
}

// ---------------- stage 1: per-block partial KVt and Ksum (no atomics) ----------------
// part_kv[blk][h*1024 + dv*32 + d]  = sum_{s in chunk} V[s][h*32+dv] * K[s][h*32+d]
// part_ks[blk][c]                   = sum_{s in chunk} K[s][c]
__global__ __launch_bounds__(1024)
void kv_partial(const unsigned short* __restrict__ Kb, const unsigned short* __restrict__ Vb,
                float* __restrict__ part_kv, float* __restrict__ part_ks) {
  __shared__ float Ks[16][256];
  __shared__ float Vs[16][256];
  const int t   = threadIdx.x;
  const int blk = blockIdx.x;
  const int n   = blk >> 6;
  const int s0  = (blk & 63) * 128;
  const int h   = t >> 7, g = (t >> 5) & 3, dv = t & 31;
  const int r16 = t >> 6, c4 = (t & 63) * 4;
  const int cbase = h * 32;
  f32x4 acc0 = {0.f, 0.f, 0.f, 0.f}, acc1 = {0.f, 0.f, 0.f, 0.f};
  float ks = 0.f;

  for (int tile = 0; tile < 8; ++tile) {
    int s = s0 + tile * 16;
    size_t gbase = ((size_t)(n * 8192 + s + r16)) * 256 + c4;
    ushort4 kk = *(const ushort4*)&Kb[gbase];
    ushort4 vv = *(const ushort4*)&Vb[gbase];
    __syncthreads();   // previous tile's compute done
    float4 kf; kf.x = bf2f(kk.x); kf.y = bf2f(kk.y); kf.z = bf2f(kk.z); kf.w = bf2f(kk.w);
    float4 vf; vf.x = bf2f(vv.x); vf.y = bf2f(vv.y); vf.z = bf2f(vv.z); vf.w = bf2f(vv.w);
    *(float4*)&Ks[r16][c4] = kf;
    *(float4*)&Vs[r16][c4] = vf;
    __syncthreads();   // tile visible
    if (t < 256) {
      #pragma unroll
      for (int r = 0; r < 16; ++r) ks += Ks[r][t];
    }
    #pragma unroll
    for (int si = 0; si < 16; ++si) {
      f32x4 k0 = *(const f32x4*)&Ks[si][cbase + g * 8];
      f32x4 k1 = *(const f32x4*)&Ks[si][cbase + g * 8 + 4];
      float vx = Vs[si][cbase + dv];
      acc0 += k0 * vx;
      acc1 += k1 * vx;
    }
  }
  // contiguous 32B per thread; each 128B line fully covered within the block
  float* dst = &part_kv[(size_t)blk * 8192 + h * 1024 + dv * 32 + g * 8];
  *(float4*)(dst + 0) = *(float4*)&acc0;
  *(float4*)(dst + 4) = *(float4*)&acc1;
  if (t < 256) part_ks[blk * 256 + t] = ks;
}

// ---------------- stage 2: reduce 64 chunk-partials ----------------
__global__ __launch_bounds__(1024)
void kv_finalize(const float* __restrict__ part_kv, const float* __restrict__ part_ks,
                 float* __restrict__ KVt, float* __restrict__ Ksum) {
  const int b = blockIdx.x, t = threadIdx.x;
  if (b < 32) {
    int n = b >> 3;
    int e = (b & 7) * 1024 + t;
    const float* p = part_kv + (size_t)n * 64 * 8192 + e;
    float s = 0.f;
    #pragma unroll 8
    for (int c = 0; c < 64; ++c) s += p[(size_t)c * 8192];
    KVt[(size_t)n * 8192 + e] = s;
  } else {
    int n = b - 32;
    if (t < 256) {
      const float* p = part_ks + n * 64 * 256 + t;
      float s = 0.f;
      #pragma unroll 8
      for (int c = 0; c < 64; ++c) s += p[c * 256];
      Ksum[n * 256 + t] = s;
    }
  }
}

// ---------------- Mb[l, h*32+dv] = (q . KVt[h][dv][:]) * S / (q . Ksum[h] + eps) ----------------
__global__ __launch_bounds__(256)
void msg_apply(const unsigned short* __restrict__ Qb, const float* __restrict__ KVt,
               const float* __restrict__ Ksum, unsigned short* __restrict__ Mb) {
  __shared__ float KVs[8192];
  __shared__ float Kss[256];
  const int t = threadIdx.x;
  const int row0 = blockIdx.x * 32;
  const int n = blockIdx.x >> 8;
  const int r = t >> 3, h = t & 7;
  for (int i = t; i < 8192; i += 256) {
    int j = i ^ (((i >> 10) & 7) << 2);          // XOR d-slot with h: bank-spread
    KVs[j] = KVt[(size_t)n * 8192 + i];
  }
  Kss[t] = Ksum[n * 256 + t];
  __syncthreads();

  const unsigned short* qp = &Qb[(size_t)(row0 + r) * 256 + h * 32];
  float q[32];
  #pragma unroll
  for (int i = 0; i < 4; ++i) {
    short8 v = *(const short8*)(qp + i * 8);
    #pragma unroll
    for (int j = 0; j < 8; ++j) q[i * 8 + j] = bf2f((unsigned short)v[j]);
  }
  float zden = 0.f;
  #pragma unroll
  for (int sl = 0; sl < 8; ++sl) {
    f32x4 kv = *(const f32x4*)&Kss[h * 32 + sl * 4];
    zden += q[sl*4+0]*kv[0] + q[sl*4+1]*kv[1] + q[sl*4+2]*kv[2] + q[sl*4+3]*kv[3];
  }
  float z = 8192.f / (zden + 1e-6f);
  const int kvbase = h * 1024;
  short8 ov[4];
  #pragma unroll
  for (int dv = 0; dv < 32; ++dv) {
    float o = 0.f;
    #pragma unroll
    for (int sl = 0; sl < 8; ++sl) {
      f32x4 kv = *(const f32x4*)&KVs[kvbase + dv * 32 + ((sl ^ h) << 2)];
      o += q[sl*4+0]*kv[0] + q[sl*4+1]*kv[1] + q[sl*4+2]*kv[2] + q[sl*4+3]*kv[3];
    }
    ov[dv >> 3][dv & 7] = (short)f2bf(o * z);
  }
  unsigned short* op = (unsigned short*)&Mb[(size_t)(row0 + r) * 256 + h * 32];
  #pragma unroll
  for (int i = 0; i < 4; ++i) *(short8*)(op + i * 8) = ov[i];
}

// ---------------- LayerNorm kernels ----------------
__device__ __forceinline__ float block_sum(float v, float* red) {
  #pragma unroll
  for (int o = 32; o; o >>= 1) v += __shfl_down(v, o, 64);
  __syncthreads();
  if ((threadIdx.x & 63) == 0) red[threadIdx.x >> 6] = v;
  __syncthreads();
  return red[0] + red[1] + red[2] + red[3];
}

__global__ __launch_bounds__(256)
void ln1_msg(const float* __restrict__ msgf, const float* __restrict__ g,
             const float* __restrict__ b, unsigned short* __restrict__ msgb) {
  __shared__ float red[4];
  int row = blockIdx.x, t = threadIdx.x;
  float v = msgf[(size_t)row * 256 + t];
  float mu  = block_sum(v, red) * (1.f / 256.f);
  float dvv = v - mu;
  float var = block_sum(dvv * dvv, red) * (1.f / 256.f);
  float y = dvv * rsqrtf(var + 1e-5f) * g[t] + b[t];
  msgb[(size_t)row * 256 + t] = f2bf(y);
}

__global__ __launch_bounds__(256)
void ln2_res(const float* __restrict__ hbuf, const float* __restrict__ x,
             const float* __restrict__ g, const float* __restrict__ b,
             float* __restrict__ out) {
  __shared__ float red[4];
  int row = blockIdx.x, t = threadIdx.x;
  float v = hbuf[(size_t)row * 256 + t];
  float mu  = block_sum(v, red) * (1.f / 256.f);
  float dvv = v - mu;
  float var = block_sum(dvv * dvv, red) * (1.f / 256.f);
  float y = dvv * rsqrtf(var + 1e-5f) * g[t] + b[t];
  out[(size_t)row * 256 + t] = x[(size_t)row * 256 + t] + y;
}

// ---------------- launch ----------------
extern "C" void kernel_launch(void* const* d_in, const int* in_sizes, int n_in,
                              void* d_out, int out_size, void* d_ws, size_t ws_size,
                              hipStream_t stream) {
  const float* x   = (const float*)d_in[0];
  const float* src = (const float*)d_in[1];
  const float* xm  = (const float*)d_in[2];
  const float* sm  = (const float*)d_in[3];
  const float* Wq  = (const float*)d_in[4];
  const float* Wk  = (const float*)d_in[5];
  const float* Wv  = (const float*)d_in[6];
  const float* Wm  = (const float*)d_in[7];
  const float* W1  = (const float*)d_in[8];
  const float* W2  = (const float*)d_in[9];
  const float* g1  = (const float*)d_in[10];
  const float* b1  = (const float*)d_in[11];
  const float* g2  = (const float*)d_in[12];
  const float* b2  = (const float*)d_in[13];
  float* out = (float*)d_out;
  char*  ws  = (char*)d_ws;

  // workspace layout (bytes), regions reused over time:
  unsigned short* xb   = (unsigned short*)(ws);                    // 0..16M   bf16(x)
  unsigned short* sb   = (unsigned short*)(ws + 16777216);         // 16..32M  bf16(src)
  unsigned short* Qb   = (unsigned short*)(ws + 33554432);         // 32..48M
  unsigned short* Mb   = (unsigned short*)(ws + 50331648);         // 48..64M
  unsigned short* Kb   = (unsigned short*)(ws + 67108864);         // 64..80M
  unsigned short* Vb   = (unsigned short*)(ws + 83886080);         // 80..96M
  float*          pkv  = (float*)(ws + 16777216);                  // 16..24.25M (sb dead by then)
  float*          pks  = (float*)(ws + 16777216 + 8388608);        // 256KB
  float*          msgf = (float*)(ws + 67108864);                  // 64..96M (after kv)
  unsigned short* msgb = (unsigned short*)(ws + 50331648);         // 48..64M (after merge gemm)
  unsigned short* h1b  = (unsigned short*)(ws + 67108864);         // 64..96M (after ln1)
  float*          h2f  = (float*)(ws);                             // 0..32M  (after mlp1)
  float*          KV   = (float*)(ws + 100663296);                 // 131072 B  (KVt[nh][dv][d])
  float*          Ksm  = (float*)(ws + 100663296 + 131072);        // 4096 B
  unsigned short* Wb   = (unsigned short*)(ws + 100663296 + 135168);
  unsigned short* Wqb = Wb;
  unsigned short* Wkb = Wb + 65536;    // Wk rows 0..255, Wv rows 256..511 (contiguous)
  unsigned short* Wmb = Wb + 196608;
  unsigned short* W1b = Wb + 262144;
  unsigned short* W2b = Wb + 524288;

  cast2_kernel<<<2048, 256, 0, stream>>>(x, src, xb, sb, 2097152);
  castw_kernel<<<2560, 256, 0, stream>>>(Wq, Wk, Wv, Wm, W1, W2, Wb);

  // projections: Q alone; K+V fused (O=512, B = [Wk;Wv])
  gemm_nt<EPI_ELU1_MASK, false><<<dim3(256, 2), 256, 0, stream>>>(
      xb, nullptr, Wqb, (void*)Qb, nullptr, xm, 32768, 256, 256, 0.f);
  gemm_nt<EPI_KV, false><<<dim3(256, 4), 256, 0, stream>>>(
      sb, nullptr, Wkb, (void*)Kb, (void*)Vb, sm, 32768, 512, 256, 1.f / 8192.f);

  // linear attention core: partial-reduce (no atomics) + finalize
  kv_partial<<<256, 1024, 0, stream>>>(Kb, Vb, pkv, pks);
  kv_finalize<<<36, 1024, 0, stream>>>(pkv, pks, KV, Ksm);
  msg_apply<<<1024, 256, 0, stream>>>(Qb, KV, Ksm, Mb);

  // merge heads + LN1
  gemm_nt<EPI_F32, false><<<dim3(256, 2), 256, 0, stream>>>(
      Mb, nullptr, Wmb, (void*)msgf, nullptr, nullptr, 32768, 256, 256, 0.f);
  ln1_msg<<<32768, 256, 0, stream>>>(msgf, g1, b1, msgb);

  // MLP: A split = [xb | msgb]
  gemm_nt<EPI_RELU_BF16, true><<<dim3(256, 4), 256, 0, stream>>>(
      xb, msgb, W1b, (void*)h1b, nullptr, nullptr, 32768, 512, 512, 0.f);
  gemm_nt<EPI_F32, false><<<dim3(256, 2), 256, 0, stream>>>(
      h1b, nullptr, W2b, (void*)h2f, nullptr, nullptr, 32768, 256, 512, 0.f);
  ln2_res<<<32768, 256, 0, stream>>>(h2f, x, g2, b2, out);
}

// Round 4
// 286.495 us; speedup vs baseline: 1.4354x; 1.1237x over previous
//
#include <hip/hip_runtime.h>

using short8 = __attribute__((ext_vector_type(8))) short;
using f32x4  = __attribute__((ext_vector_type(4))) float;

__device__ __forceinline__ float bf2f(unsigned short u) {
  union { unsigned int i; float f; } c; c.i = ((unsigned int)u) << 16; return c.f;
}
__device__ __forceinline__ unsigned short f2bf(float x) {
  union { float f; unsigned int i; } c; c.f = x;
  unsigned int r = c.i + 0x7fffu + ((c.i >> 16) & 1u);
  return (unsigned short)(r >> 16);
}

// ---------------- fused cast kernel: x, src, and all weights -> bf16 ----------------
__global__ void cast_all(const float* __restrict__ x, const float* __restrict__ src,
                         const float* __restrict__ wq, const float* __restrict__ wk,
                         const float* __restrict__ wv, const float* __restrict__ wm,
                         const float* __restrict__ w1, const float* __restrict__ w2,
                         unsigned short* __restrict__ xb, unsigned short* __restrict__ sb,
                         unsigned short* __restrict__ Wb) {
  const int NV = 2097152;              // vec4 count for x and for src
  int stride = gridDim.x * blockDim.x;
  for (int i = blockIdx.x * blockDim.x + threadIdx.x; i < 2 * NV + 163840; i += stride) {
    const float4* s; ushort4* d; int j;
    if (i < NV)            { s = (const float4*)x;   d = (ushort4*)xb; j = i; }
    else if (i < 2 * NV)   { s = (const float4*)src; d = (ushort4*)sb; j = i - NV; }
    else {
      j = i - 2 * NV;                  // 0..163839 vec4s of weights
      d = (ushort4*)Wb;
      const float* w;
      int off;
      if      (j < 16384)  { w = wq; off = j; }
      else if (j < 32768)  { w = wk; off = j - 16384; }
      else if (j < 49152)  { w = wv; off = j - 32768; }
      else if (j < 65536)  { w = wm; off = j - 49152; }
      else if (j < 131072) { w = w1; off = j - 65536; }
      else                 { w = w2; off = j - 131072; }
      float4 v = ((const float4*)w)[off];
      ushort4 o; o.x = f2bf(v.x); o.y = f2bf(v.y); o.z = f2bf(v.z); o.w = f2bf(v.w);
      d[j] = o;
      continue;
    }
    float4 v = s[j];
    ushort4 o; o.x = f2bf(v.x); o.y = f2bf(v.y); o.z = f2bf(v.z); o.w = f2bf(v.w);
    d[j] = o;
  }
}

// ---------------- GEMM: C[M,O] = A[M,K] @ B[O,K]^T, bf16 in, f32 accum ----------------
enum { EPI_ELU1_MASK = 1, EPI_KV = 2, EPI_RELU_BF16 = 3 };

template<int EPI, bool SPLITA>
__global__ __launch_bounds__(256)
void gemm_nt(const unsigned short* __restrict__ A, const unsigned short* __restrict__ A2,
             const unsigned short* __restrict__ B,
             void* __restrict__ C0, void* __restrict__ C1, const float* __restrict__ aux,
             int M, int O, int K, float scale) {
  __shared__ unsigned short As[128 * 64];
  __shared__ unsigned short Bs[128 * 64];
  const int t  = threadIdx.x;
  const int w  = t >> 6, l = t & 63;
  const int wr = w >> 1, wc = w & 1;
  const int lr = l & 15, kg = l >> 4;
  const int brow = blockIdx.x * 128, bcol = blockIdx.y * 128;
  const int rsub = l >> 3;                       // 0..7 (row within 8-row chunk)
  const int swz  = 8 * ((l & 7) ^ rsub);         // pre-swizzled source col (elems)

  f32x4 acc[4][4];
  f32x4 zero = {0.f, 0.f, 0.f, 0.f};
  #pragma unroll
  for (int m = 0; m < 4; m++)
    #pragma unroll
    for (int n = 0; n < 4; n++) acc[m][n] = zero;

  for (int k0 = 0; k0 < K; k0 += 64) {
    #pragma unroll
    for (int i = 0; i < 4; i++) {
      int c = w * 4 + i;                         // chunk 0..15, 1KB each
      int row = c * 8 + rsub;
      const unsigned short* ga;
      if (SPLITA) {
        const unsigned short* base = (k0 < 256) ? A : A2;
        ga = base + (size_t)(brow + row) * 256 + (k0 & 255) + swz;
      } else {
        ga = A + (size_t)(brow + row) * K + k0 + swz;
      }
      const unsigned short* gb = B + (size_t)(bcol + row) * K + k0 + swz;
      __builtin_amdgcn_global_load_lds((__attribute__((address_space(1))) unsigned int*)ga,
          (__attribute__((address_space(3))) unsigned int*)(As + c * 512), 16, 0, 0);
      __builtin_amdgcn_global_load_lds((__attribute__((address_space(1))) unsigned int*)gb,
          (__attribute__((address_space(3))) unsigned int*)(Bs + c * 512), 16, 0, 0);
    }
    __syncthreads();
    #pragma unroll
    for (int kk = 0; kk < 2; kk++) {
      short8 af[4], bfr[4];
      #pragma unroll
      for (int m = 0; m < 4; m++) {
        int r = wr * 64 + m * 16 + lr;
        int cb = kk * 64 + kg * 16;
        af[m] = *(const short8*)((const char*)As + r * 128 + (cb ^ ((r & 7) << 4)));
      }
      #pragma unroll
      for (int n = 0; n < 4; n++) {
        int r = wc * 64 + n * 16 + lr;
        int cb = kk * 64 + kg * 16;
        bfr[n] = *(const short8*)((const char*)Bs + r * 128 + (cb ^ ((r & 7) << 4)));
      }
      #pragma unroll
      for (int m = 0; m < 4; m++)
        #pragma unroll
        for (int n = 0; n < 4; n++)
          acc[m][n] = __builtin_amdgcn_mfma_f32_16x16x32_bf16(af[m], bfr[n], acc[m][n], 0, 0, 0);
    }
    __syncthreads();
  }

  #pragma unroll
  for (int m = 0; m < 4; m++) {
    #pragma unroll
    for (int n = 0; n < 4; n++) {
      int col = bcol + wc * 64 + n * 16 + lr;
      #pragma unroll
      for (int j = 0; j < 4; j++) {
        int row = brow + wr * 64 + m * 16 + kg * 4 + j;
        float v = acc[m][n][j];
        if (EPI == EPI_ELU1_MASK) {
          float e = v > 0.f ? v + 1.f : __expf(v);   // elu(v)+1
          ((unsigned short*)C0)[(size_t)row * O + col] = f2bf(e * aux[row]);
        } else if (EPI == EPI_KV) {
          int colm = col & 255;
          if (col < 256) {                           // K path: elu+1, mask
            float e = v > 0.f ? v + 1.f : __expf(v);
            ((unsigned short*)C0)[(size_t)row * 256 + colm] = f2bf(e * aux[row]);
          } else {                                   // V path: mask * 1/S
            ((unsigned short*)C1)[(size_t)row * 256 + colm] = f2bf(v * aux[row] * scale);
          }
        } else {  // EPI_RELU_BF16
          ((unsigned short*)C0)[(size_t)row * O + col] = f2bf(v > 0.f ? v : 0.f);
        }
      }
    }
  }
}

// ---------------- GEMM + row LayerNorm fused. Tile 128 x 256 (full O), 8 waves ----------------
// MODE 0: Cout = bf16( LN(A@B^T) * g + b )
// MODE 1: Cout = f32 ( xres + LN(A@B^T) * g + b )
template<int MODE>
__global__ __launch_bounds__(512)
void gemm_ln(const unsigned short* __restrict__ A, const unsigned short* __restrict__ B,
             void* __restrict__ Cout, const float* __restrict__ g, const float* __restrict__ b,
             const float* __restrict__ xres, int K) {
  __shared__ unsigned short As[128 * 64];    // 16 KB
  __shared__ unsigned short Bs[256 * 64];    // 32 KB
  __shared__ float lnsum[128][4];
  __shared__ float lnsq[128][4];
  const int t  = threadIdx.x;
  const int w  = t >> 6, l = t & 63;
  const int wr = w >> 2, wc = w & 3;         // 2 row-waves x 4 col-waves
  const int lr = l & 15, kg = l >> 4;
  const int brow = blockIdx.x * 128;
  const int rsub = l >> 3;
  const int swz  = 8 * ((l & 7) ^ rsub);

  f32x4 acc[4][4];
  f32x4 zero = {0.f, 0.f, 0.f, 0.f};
  #pragma unroll
  for (int m = 0; m < 4; m++)
    #pragma unroll
    for (int n = 0; n < 4; n++) acc[m][n] = zero;

  for (int k0 = 0; k0 < K; k0 += 64) {
    #pragma unroll
    for (int i = 0; i < 6; i++) {            // 48 chunks / 8 waves
      int c = w * 6 + i;
      if (c < 16) {
        int row = c * 8 + rsub;
        const unsigned short* ga = A + (size_t)(brow + row) * K + k0 + swz;
        __builtin_amdgcn_global_load_lds((__attribute__((address_space(1))) unsigned int*)ga,
            (__attribute__((address_space(3))) unsigned int*)(As + c * 512), 16, 0, 0);
      } else {
        int row = (c - 16) * 8 + rsub;
        const unsigned short* gb = B + (size_t)row * K + k0 + swz;
        __builtin_amdgcn_global_load_lds((__attribute__((address_space(1))) unsigned int*)gb,
            (__attribute__((address_space(3))) unsigned int*)(Bs + (c - 16) * 512), 16, 0, 0);
      }
    }
    __syncthreads();
    #pragma unroll
    for (int kk = 0; kk < 2; kk++) {
      short8 af[4], bfr[4];
      #pragma unroll
      for (int m = 0; m < 4; m++) {
        int r = wr * 64 + m * 16 + lr;
        int cb = kk * 64 + kg * 16;
        af[m] = *(const short8*)((const char*)As + r * 128 + (cb ^ ((r & 7) << 4)));
      }
      #pragma unroll
      for (int n = 0; n < 4; n++) {
        int r = wc * 64 + n * 16 + lr;
        int cb = kk * 64 + kg * 16;
        bfr[n] = *(const short8*)((const char*)Bs + r * 128 + (cb ^ ((r & 7) << 4)));
      }
      #pragma unroll
      for (int m = 0; m < 4; m++)
        #pragma unroll
        for (int n = 0; n < 4; n++)
          acc[m][n] = __builtin_amdgcn_mfma_f32_16x16x32_bf16(af[m], bfr[n], acc[m][n], 0, 0, 0);
    }
    __syncthreads();
  }

  // per-row partial sums (this wave covers 64 cols of each of its 64 rows)
  #pragma unroll
  for (int m = 0; m < 4; m++) {
    #pragma unroll
    for (int j = 0; j < 4; j++) {
      int rl = wr * 64 + m * 16 + kg * 4 + j;
      float s = 0.f, qq = 0.f;
      #pragma unroll
      for (int n = 0; n < 4; n++) { float v = acc[m][n][j]; s += v; qq += v * v; }
      #pragma unroll
      for (int off = 1; off < 16; off <<= 1) {
        s  += __shfl_xor(s, off, 64);
        qq += __shfl_xor(qq, off, 64);
      }
      if (lr == 0) { lnsum[rl][wc] = s; lnsq[rl][wc] = qq; }
    }
  }
  __syncthreads();

  float gl[4], bl[4];
  #pragma unroll
  for (int n = 0; n < 4; n++) {
    int col = wc * 64 + n * 16 + lr;
    gl[n] = g[col]; bl[n] = b[col];
  }
  #pragma unroll
  for (int m = 0; m < 4; m++) {
    #pragma unroll
    for (int j = 0; j < 4; j++) {
      int rl = wr * 64 + m * 16 + kg * 4 + j;
      float s  = lnsum[rl][0] + lnsum[rl][1] + lnsum[rl][2] + lnsum[rl][3];
      float qq = lnsq[rl][0] + lnsq[rl][1] + lnsq[rl][2] + lnsq[rl][3];
      float mu = s * (1.f / 256.f);
      float var = qq * (1.f / 256.f) - mu * mu;
      float rs = rsqrtf(var + 1e-5f);
      size_t row = (size_t)brow + rl;
      #pragma unroll
      for (int n = 0; n < 4; n++) {
        int col = wc * 64 + n * 16 + lr;
        float y = (acc[m][n][j] - mu) * rs * gl[n] + bl[n];
        if (MODE == 0) ((unsigned short*)Cout)[row * 256 + col] = f2bf(y);
        else           ((float*)Cout)[row * 256 + col] = xres[row * 256 + col] + y;
      }
    }
  }
}

// ---------------- stage 1: per-block partial KVt and Ksum (no atomics) ----------------
__global__ __launch_bounds__(1024)
void kv_partial(const unsigned short* __restrict__ Kb, const unsigned short* __restrict__ Vb,
                float* __restrict__ part_kv, float* __restrict__ part_ks) {
  __shared__ float Ks[16][256];
  __shared__ float Vs[16][256];
  const int t   = threadIdx.x;
  const int blk = blockIdx.x;
  const int n   = blk >> 6;
  const int s0  = (blk & 63) * 128;
  const int h   = t >> 7, g = (t >> 5) & 3, dv = t & 31;
  const int r16 = t >> 6, c4 = (t & 63) * 4;
  const int cbase = h * 32;
  f32x4 acc0 = {0.f, 0.f, 0.f, 0.f}, acc1 = {0.f, 0.f, 0.f, 0.f};
  float ks = 0.f;

  for (int tile = 0; tile < 8; ++tile) {
    int s = s0 + tile * 16;
    size_t gbase = ((size_t)(n * 8192 + s + r16)) * 256 + c4;
    ushort4 kk = *(const ushort4*)&Kb[gbase];
    ushort4 vv = *(const ushort4*)&Vb[gbase];
    __syncthreads();
    float4 kf; kf.x = bf2f(kk.x); kf.y = bf2f(kk.y); kf.z = bf2f(kk.z); kf.w = bf2f(kk.w);
    float4 vf; vf.x = bf2f(vv.x); vf.y = bf2f(vv.y); vf.z = bf2f(vv.z); vf.w = bf2f(vv.w);
    *(float4*)&Ks[r16][c4] = kf;
    *(float4*)&Vs[r16][c4] = vf;
    __syncthreads();
    if (t < 256) {
      #pragma unroll
      for (int r = 0; r < 16; ++r) ks += Ks[r][t];
    }
    #pragma unroll
    for (int si = 0; si < 16; ++si) {
      f32x4 k0 = *(const f32x4*)&Ks[si][cbase + g * 8];
      f32x4 k1 = *(const f32x4*)&Ks[si][cbase + g * 8 + 4];
      float vx = Vs[si][cbase + dv];
      acc0 += k0 * vx;
      acc1 += k1 * vx;
    }
  }
  float* dst = &part_kv[(size_t)blk * 8192 + h * 1024 + dv * 32 + g * 8];
  *(float4*)(dst + 0) = *(float4*)&acc0;
  *(float4*)(dst + 4) = *(float4*)&acc1;
  if (t < 256) part_ks[blk * 256 + t] = ks;
}

// ---------------- stage 2: reduce 64 chunk-partials ----------------
__global__ __launch_bounds__(1024)
void kv_finalize(const float* __restrict__ part_kv, const float* __restrict__ part_ks,
                 float* __restrict__ KVt, float* __restrict__ Ksum) {
  const int b = blockIdx.x, t = threadIdx.x;
  if (b < 32) {
    int n = b >> 3;
    int e = (b & 7) * 1024 + t;
    const float* p = part_kv + (size_t)n * 64 * 8192 + e;
    float s = 0.f;
    #pragma unroll 8
    for (int c = 0; c < 64; ++c) s += p[(size_t)c * 8192];
    KVt[(size_t)n * 8192 + e] = s;
  } else {
    int n = b - 32;
    if (t < 256) {
      const float* p = part_ks + n * 64 * 256 + t;
      float s = 0.f;
      #pragma unroll 8
      for (int c = 0; c < 64; ++c) s += p[c * 256];
      Ksum[n * 256 + t] = s;
    }
  }
}

// ---------------- Mb[l, h*32+dv] = (q . KVt[h][dv][:]) * S / (q . Ksum[h] + eps) ----------------
__global__ __launch_bounds__(256)
void msg_apply(const unsigned short* __restrict__ Qb, const float* __restrict__ KVt,
               const float* __restrict__ Ksum, unsigned short* __restrict__ Mb) {
  __shared__ float KVs[8192];
  __shared__ float Kss[256];
  const int t = threadIdx.x;
  const int row0 = blockIdx.x * 32;
  const int n = blockIdx.x >> 8;
  const int r = t >> 3, h = t & 7;
  for (int i = t; i < 8192; i += 256) {
    int j = i ^ (((i >> 10) & 7) << 2);          // XOR d-slot with h: bank-spread
    KVs[j] = KVt[(size_t)n * 8192 + i];
  }
  Kss[t] = Ksum[n * 256 + t];
  __syncthreads();

  const unsigned short* qp = &Qb[(size_t)(row0 + r) * 256 + h * 32];
  float q[32];
  #pragma unroll
  for (int i = 0; i < 4; ++i) {
    short8 v = *(const short8*)(qp + i * 8);
    #pragma unroll
    for (int j = 0; j < 8; ++j) q[i * 8 + j] = bf2f((unsigned short)v[j]);
  }
  float zden = 0.f;
  #pragma unroll
  for (int sl = 0; sl < 8; ++sl) {
    f32x4 kv = *(const f32x4*)&Kss[h * 32 + sl * 4];
    zden += q[sl*4+0]*kv[0] + q[sl*4+1]*kv[1] + q[sl*4+2]*kv[2] + q[sl*4+3]*kv[3];
  }
  float z = 8192.f / (zden + 1e-6f);
  const int kvbase = h * 1024;
  short8 ov[4];
  #pragma unroll
  for (int dv = 0; dv < 32; ++dv) {
    float o = 0.f;
    #pragma unroll
    for (int sl = 0; sl < 8; ++sl) {
      f32x4 kv = *(const f32x4*)&KVs[kvbase + dv * 32 + ((sl ^ h) << 2)];
      o += q[sl*4+0]*kv[0] + q[sl*4+1]*kv[1] + q[sl*4+2]*kv[2] + q[sl*4+3]*kv[3];
    }
    ov[dv >> 3][dv & 7] = (short)f2bf(o * z);
  }
  unsigned short* op = (unsigned short*)&Mb[(size_t)(row0 + r) * 256 + h * 32];
  #pragma unroll
  for (int i = 0; i < 4; ++i) *(short8*)(op + i * 8) = ov[i];
}

// ---------------- launch ----------------
extern "C" void kernel_launch(void* const* d_in, const int* in_sizes, int n_in,
                              void* d_out, int out_size, void* d_ws, size_t ws_size,
                              hipStream_t stream) {
  const float* x   = (const float*)d_in[0];
  const float* src = (const float*)d_in[1];
  const float* xm  = (const float*)d_in[2];
  const float* sm  = (const float*)d_in[3];
  const float* Wq  = (const float*)d_in[4];
  const float* Wk  = (const float*)d_in[5];
  const float* Wv  = (const float*)d_in[6];
  const float* Wm  = (const float*)d_in[7];
  const float* W1  = (const float*)d_in[8];
  const float* W2  = (const float*)d_in[9];
  const float* g1  = (const float*)d_in[10];
  const float* b1  = (const float*)d_in[11];
  const float* g2  = (const float*)d_in[12];
  const float* b2  = (const float*)d_in[13];
  float* out = (float*)d_out;
  char*  ws  = (char*)d_ws;

  // workspace layout (bytes), regions reused over time:
  unsigned short* xb   = (unsigned short*)(ws);                    // 0..16M    bf16(x), live to mlp1
  unsigned short* sb   = (unsigned short*)(ws + 16777216);         // 16..32M   bf16(src), dead after KV gemm
  unsigned short* Qb   = (unsigned short*)(ws + 33554432);         // 32..48M   dead after msg_apply
  unsigned short* Mb   = (unsigned short*)(ws + 50331648);         // 48..64M   dead after merge
  unsigned short* Kb   = (unsigned short*)(ws + 67108864);         // 64..80M   dead after kv_partial
  unsigned short* Vb   = (unsigned short*)(ws + 83886080);         // 80..96M   dead after kv_partial
  float*          pkv  = (float*)(ws + 16777216);                  // overlays sb (8.4MB)
  float*          pks  = (float*)(ws + 16777216 + 8388608);        // 256KB
  unsigned short* msgb = (unsigned short*)(ws + 67108864);         // overlays Kb
  unsigned short* h1b  = (unsigned short*)(ws + 33554432);         // overlays Qb+Mb (32MB)
  float*          KV   = (float*)(ws + 100663296);                 // 131072 B  (KVt[nh][dv][d])
  float*          Ksm  = (float*)(ws + 100663296 + 131072);        // 4096 B
  unsigned short* Wb   = (unsigned short*)(ws + 100663296 + 135168);
  unsigned short* Wqb = Wb;
  unsigned short* Wkb = Wb + 65536;    // Wk rows 0..255, Wv rows 256..511 (contiguous)
  unsigned short* Wmb = Wb + 196608;
  unsigned short* W1b = Wb + 262144;
  unsigned short* W2b = Wb + 524288;

  cast_all<<<4096, 256, 0, stream>>>(x, src, Wq, Wk, Wv, Wm, W1, W2, xb, sb, Wb);

  // projections: Q alone; K+V fused (O=512, B = [Wk;Wv])
  gemm_nt<EPI_ELU1_MASK, false><<<dim3(256, 2), 256, 0, stream>>>(
      xb, nullptr, Wqb, (void*)Qb, nullptr, xm, 32768, 256, 256, 0.f);
  gemm_nt<EPI_KV, false><<<dim3(256, 4), 256, 0, stream>>>(
      sb, nullptr, Wkb, (void*)Kb, (void*)Vb, sm, 32768, 512, 256, 1.f / 8192.f);

  // linear attention core: partial-reduce (no atomics) + finalize
  kv_partial<<<256, 1024, 0, stream>>>(Kb, Vb, pkv, pks);
  kv_finalize<<<36, 1024, 0, stream>>>(pkv, pks, KV, Ksm);
  msg_apply<<<1024, 256, 0, stream>>>(Qb, KV, Ksm, Mb);

  // merge heads + LN1 fused -> msgb (bf16)
  gemm_ln<0><<<256, 512, 0, stream>>>(Mb, Wmb, (void*)msgb, g1, b1, nullptr, 256);

  // MLP: A split = [xb | msgb]
  gemm_nt<EPI_RELU_BF16, true><<<dim3(256, 4), 256, 0, stream>>>(
      xb, msgb, W1b, (void*)h1b, nullptr, nullptr, 32768, 512, 512, 0.f);

  // mlp2 + LN2 + residual fused -> out (f32)
  gemm_ln<1><<<256, 512, 0, stream>>>(h1b, W2b, (void*)out, g2, b2, x, 512);
}